// Round 4
// baseline (42.795 us; speedup 1.0000x reference)
//
#include <hip/hip_runtime.h>

// im2col permuted copy, fp32:
//   x: (16, 3, 512, 512); K=8, S=4, P=0; Ho=Wo=127
//   out[b, ho*127+wo, c, kh*8+kw] = x[b, c, ho*4+kh, wo*4+kw]
//
// One workgroup per (b, ho):
//   load  : 3 x 16KB contiguous channel blocks -> LDS (coalesced float4)
//   store : one contiguous 95.25KB output region <- LDS (coalesced float4)
// R4 = R3 with the nontemporal store fixed: __builtin_nontemporal_store
// requires a NATIVE vector type (ext_vector_type), not HIP_vector_type.

namespace {
typedef float f32x4 __attribute__((ext_vector_type(4)));

constexpr int B  = 16;
constexpr int C  = 3;
constexpr int H  = 512;
constexpr int W  = 512;
constexpr int S  = 4;
constexpr int Ho = 127;
constexpr int Wo = 127;
constexpr int P  = Ho * Wo;
constexpr int ROW_PAD = W + 4;                  // 516 floats
constexpr int LDS_FLOATS = C * 8 * ROW_PAD;     // 48.4 KB
constexpr int IN_F4_PER_C = 8 * W / 4;          // 1024 float4 / channel block
constexpr int IN_F4 = C * IN_F4_PER_C;          // 3072
constexpr int OUT_F4_PER_GROUP = Wo * C * 16;   // 6096 float4 / (b,ho)
constexpr int NWG = B * Ho;                     // 2032 = 8 * 254
constexpr int TPB = 512;
}

__global__ __launch_bounds__(TPB) void
PatchesKernel3D_34892314313629_kernel(const float* __restrict__ x,
                                      float* __restrict__ out) {
    __shared__ float lds[LDS_FLOATS];

    // XCD-bijective swizzle (2032 % 8 == 0): consecutive logical ids share
    // 4 of 8 input rows -> L2 hits within an XCD.
    const int bid = (int)blockIdx.x;
    const int logical = (bid & 7) * (NWG / 8) + (bid >> 3);
    const int b  = logical / Ho;
    const int ho = logical - b * Ho;

    const int tid = (int)threadIdx.x;

    // ---- Phase 1: global -> LDS, coalesced ----
    const f32x4* __restrict__ x4 = reinterpret_cast<const f32x4*>(x);
    #pragma unroll
    for (int l = tid; l < IN_F4; l += TPB) {
        const int c = l >> 10;               // /1024
        const int r = l & 1023;
        const size_t src4 =
            ((size_t)((b * C + c) * H + ho * S) * W) / 4 + r;
        const f32x4 v = x4[src4];
        const int row  = r >> 7;             // 128 float4 per row
        const int col4 = r & 127;
        *reinterpret_cast<f32x4*>(
            &lds[c * 8 * ROW_PAD + row * ROW_PAD + col4 * 4]) = v;
    }

    __syncthreads();

    // ---- Phase 2: LDS -> global, coalesced nontemporal ----
    f32x4* __restrict__ out4 = reinterpret_cast<f32x4*>(out);
    const size_t out_base4 = ((size_t)(b * P + ho * Wo) * C) * 16;

    for (int o = tid; o < OUT_F4_PER_GROUP; o += TPB) {
        const int j  = o & 15;
        const int q  = o >> 4;               // wo*3 + c
        const int c  = q % 3;
        const int wo = q / 3;
        const int kh  = j >> 1;
        const int kw0 = (j & 1) << 2;
        const f32x4 v = *reinterpret_cast<const f32x4*>(
            &lds[c * 8 * ROW_PAD + kh * ROW_PAD + wo * S + kw0]);
        __builtin_nontemporal_store(v, &out4[out_base4 + o]);
    }
}

extern "C" void kernel_launch(void* const* d_in, const int* in_sizes, int n_in,
                              void* d_out, int out_size, void* d_ws, size_t ws_size,
                              hipStream_t stream) {
    const float* x = (const float*)d_in[0];
    float* out = (float*)d_out;
    PatchesKernel3D_34892314313629_kernel<<<NWG, TPB, 0, stream>>>(x, out);
}

// Round 5
// 42.321 us; speedup vs baseline: 1.0112x; 1.0112x over previous
//
#include <hip/hip_runtime.h>

// im2col permuted copy, fp32:
//   x: (16, 3, 512, 512); K=8, S=4, P=0; Ho=Wo=127
//   out[b, ho*127+wo, c, kh*8+kw] = x[b, c, ho*4+kh, wo*4+kw]
//
// R5: one workgroup per (b, ho, c)  [R2 was per (b, ho)]
//   load  : one contiguous 16 KB input block (8 rows) -> LDS (coalesced f32x4)
//   store : 127 runs of 256 B at stride 768 B <- LDS (cache-line coalesced)
//   LDS = 16.5 KB -> 8 WGs/CU (32-wave occupancy cap) vs 3 before: eight
//   independently-phased WGs interleave their load/store bursts per CU,
//   keeping both memory directions busy without explicit double-buffering.

namespace {
typedef float f32x4 __attribute__((ext_vector_type(4)));

constexpr int B  = 16;
constexpr int C  = 3;
constexpr int H  = 512;
constexpr int W  = 512;
constexpr int S  = 4;
constexpr int Ho = 127;
constexpr int Wo = 127;
constexpr int P  = Ho * Wo;
constexpr int ROW_PAD = W + 4;                  // 516 floats: kh*516 mod 32 spreads bank-quads
constexpr int LDS_FLOATS = 8 * ROW_PAD;         // 16.5 KB
constexpr int IN_F4  = 8 * W / 4;               // 1024 f32x4 per group (16 KB)
constexpr int OUT_F4 = Wo * 16;                 // 2032 f32x4 per group
constexpr int NWG = B * Ho * C;                 // 6096 = 8 * 762
constexpr int TPB = 256;
}

__global__ __launch_bounds__(TPB) void
PatchesKernel3D_34892314313629_kernel(const float* __restrict__ x,
                                      float* __restrict__ out) {
    __shared__ float lds[LDS_FLOATS];

    // XCD-bijective swizzle (6096 % 8 == 0). Group order: c fastest, then ho
    // -> ho-adjacent groups (sharing 4 of 8 input rows) stay on one XCD's L2.
    const int bid = (int)blockIdx.x;
    const int logical = (bid & 7) * (NWG / 8) + (bid >> 3);
    const int c  = logical % C;
    const int t  = logical / C;            // b*Ho + ho
    const int ho = t % Ho;
    const int b  = t / Ho;

    const int tid = (int)threadIdx.x;

    // ---- Phase 1: global -> LDS, one contiguous 16 KB block ----
    const f32x4* __restrict__ x4 = reinterpret_cast<const f32x4*>(x);
    const size_t src_base4 = ((size_t)((b * C + c) * H + ho * S) * W) / 4;
    #pragma unroll
    for (int l = tid; l < IN_F4; l += TPB) {   // 4 iterations
        const f32x4 v = x4[src_base4 + l];
        const int row  = l >> 7;               // 128 f32x4 per row
        const int col4 = l & 127;
        *reinterpret_cast<f32x4*>(&lds[row * ROW_PAD + col4 * 4]) = v;
    }

    __syncthreads();

    // ---- Phase 2: LDS -> global ----
    // out4 index = ((b*P + ho*Wo + wo)*C + c)*16 + j = base + wo*48 + j
    f32x4* __restrict__ out4 = reinterpret_cast<f32x4*>(out);
    const size_t out_base4 = ((size_t)(b * P + ho * Wo) * C + c) * 16;

    for (int o = tid; o < OUT_F4; o += TPB) {  // 8 iterations, last partial
        const int j  = o & 15;                 // f32x4 within the 64-elem kk dim
        const int wo = o >> 4;
        const int kh  = j >> 1;
        const int kw0 = (j & 1) << 2;
        const f32x4 v = *reinterpret_cast<const f32x4*>(
            &lds[kh * ROW_PAD + wo * S + kw0]);
        out4[out_base4 + wo * 48 + j] = v;
    }
}

extern "C" void kernel_launch(void* const* d_in, const int* in_sizes, int n_in,
                              void* d_out, int out_size, void* d_ws, size_t ws_size,
                              hipStream_t stream) {
    const float* x = (const float*)d_in[0];
    float* out = (float*)d_out;
    PatchesKernel3D_34892314313629_kernel<<<NWG, TPB, 0, stream>>>(x, out);
}